// Round 1
// baseline (445.869 us; speedup 1.0000x reference)
//
#include <hip/hip_runtime.h>
#include <hip/hip_cooperative_groups.h>
#include <math.h>

namespace cg = cooperative_groups;

// Problem constants (fixed by the reference)
constexpr int NG    = 128;          // graphs
constexpr int NP    = 1024;         // nodes per graph
constexpr int D     = 256;          // feature dim
constexpr int NTOT  = NG * NP;      // 131072 nodes
constexpr int EPG   = NP * 32;      // 32768 edges per graph (contiguous slice)
constexpr int ET    = NTOT * 32;    // 4194304 edges
constexpr int KK    = 820;          // kept per graph
constexpr int NKEEP = NG * KK;      // 104960 kept nodes

// Fused-kernel geometry: 256 blocks x 1024 threads, cooperative (1 block/CU)
constexpr int NBLK  = 256;
constexpr int EHALF = EPG / 2;          // 16384 edges per block (2 blocks/graph)
constexpr int ROWS_PER_BLK  = NTOT  / NBLK;   // 512 rows (h pass)
constexpr int GROWS_PER_BLK = NKEEP / NBLK;   // 410 rows (gather pass)

// Output layout (flat float32, reference return order)
constexpr long long OUT_X     = 0;
constexpr long long OUT_EI0   = (long long)NKEEP * D;     // 26869760
constexpr long long OUT_EI1   = OUT_EI0 + ET;
constexpr long long OUT_MASK  = OUT_EI0 + 2LL * ET;
constexpr long long OUT_BATCH = OUT_MASK + ET;
constexpr long long OUT_PERM  = OUT_BATCH + NKEEP;        // total 39662592

// ---------------------------------------------------------------------------
// Single cooperative kernel. Phases separated by grid.sync():
//   P1: h[i] = x[i,:]@W (wave/row, float4) + new_id=-1  |  degree partials
//   P2: u = rsqrt(deg)*h ; acc[c] += u[r] (LDS atomics) -> acc partials
//   P3: score -> register bitonic top-k -> perm/new_id/factor/out_perm/batch
//   P4: gather x_new = x[perm]*tanh(score)  |  edge remap via LDS new_id slice
// LDS: sk (8KB, aliased as cnt/ul+acc/nid) + scl (4KB) = 12.3 KB -> 1 blk/CU ok.
__global__ __launch_bounds__(1024, 4) void fused_kernel(
        const float* __restrict__ x,   const int* __restrict__ rows,
        const int* __restrict__ cols,  const float* __restrict__ W,
        const float* __restrict__ bptr,
        float* __restrict__ h,         int* __restrict__ new_id,
        int* __restrict__ perm_i,      float* __restrict__ factor,
        int* __restrict__ deg_part,    float* __restrict__ acc_part,
        float* __restrict__ out) {
    cg::grid_group grid = cg::this_grid();

    __shared__ unsigned long long sk[NP];   // 8 KB, multi-purpose
    __shared__ float scl[NP];               // 4 KB, scores for epilogue tanh

    const int blk  = blockIdx.x;            // 0..255
    const int t    = threadIdx.x;           // 0..1023
    const int w    = t >> 6;                // wave 0..15
    const int lane = t & 63;
    const int g2   = blk >> 1;              // graph for edge-slice phases
    const int half = blk & 1;               // which 16384-edge half

    // ---------------- P1: h rows + degree partials -------------------------
    {
        int* cnt = (int*)sk;
        for (int i = t; i < NP; i += 1024) cnt[i] = 0;
        __syncthreads();

        // h pass: one wave per row, float4 loads (16 B/lane, 1 KB/row)
        float4 w4 = ((const float4*)W)[lane];
        const int base = blk * ROWS_PER_BLK;
        for (int r = w; r < ROWS_PER_BLK; r += 16) {
            const int row = base + r;
            float4 a = ((const float4*)(x + (size_t)row * D))[lane];
            float s = a.x * w4.x + a.y * w4.y + a.z * w4.z + a.w * w4.w;
#pragma unroll
            for (int off = 32; off > 0; off >>= 1) s += __shfl_down(s, off, 64);
            if (lane == 0) { h[row] = s; new_id[row] = -1; }
        }

        // degree partials over this block's 16384-edge slice
        const int4* c4 = (const int4*)(cols + (size_t)g2 * EPG + (size_t)half * EHALF);
#pragma unroll
        for (int i = t; i < EHALF / 4; i += 1024) {     // 4 iters
            int4 c = c4[i];
            atomicAdd(&cnt[c.x & (NP - 1)], 1);
            atomicAdd(&cnt[c.y & (NP - 1)], 1);
            atomicAdd(&cnt[c.z & (NP - 1)], 1);
            atomicAdd(&cnt[c.w & (NP - 1)], 1);
        }
        __syncthreads();
        int* dst = deg_part + (size_t)blk * NP;
        for (int i = t; i < NP; i += 1024) dst[i] = cnt[i];
    }
    grid.sync();

    // ---------------- P2: aggregation partials -----------------------------
    {
        float* ul  = (float*)sk;            // 4 KB
        float* acc = (float*)sk + NP;       // 4 KB
        const int* dp = deg_part + (size_t)(2 * g2) * NP;
        for (int i = t; i < NP; i += 1024) {
            int d  = 1 + dp[i] + dp[NP + i];
            ul[i]  = rsqrtf((float)d) * h[g2 * NP + i];
            acc[i] = 0.0f;
        }
        __syncthreads();
        const size_t eo = (size_t)g2 * EPG + (size_t)half * EHALF;
        const int4* c4 = (const int4*)(cols + eo);
        const int4* r4 = (const int4*)(rows + eo);
#pragma unroll
        for (int i = t; i < EHALF / 4; i += 1024) {     // 4 iters
            int4 c = c4[i];
            int4 r = r4[i];
            atomicAdd(&acc[c.x & (NP - 1)], ul[r.x & (NP - 1)]);
            atomicAdd(&acc[c.y & (NP - 1)], ul[r.y & (NP - 1)]);
            atomicAdd(&acc[c.z & (NP - 1)], ul[r.z & (NP - 1)]);
            atomicAdd(&acc[c.w & (NP - 1)], ul[r.w & (NP - 1)]);
        }
        __syncthreads();
        float* dst = acc_part + (size_t)blk * NP;
        for (int i = t; i < NP; i += 1024) dst[i] = acc[i];
    }
    grid.sync();

    // ---------------- P3: score + bitonic top-k + epilogue -----------------
    if (blk < NG) {
        const int g = blk;
        const int*   dp = deg_part + (size_t)(2 * g) * NP;
        const float* ap = acc_part + (size_t)(2 * g) * NP;
        int   d  = 1 + dp[t] + dp[NP + t];
        float av = ap[t] + ap[NP + t];
        float hv = h[g * NP + t];
        float di = rsqrtf((float)d);
        float score = di * av + di * di * hv + bptr[0];
        scl[t] = score;

        // sortable key: ascending u64 == (descending score, ascending idx)
        unsigned int fu = __float_as_uint(score);
        unsigned int s  = (fu & 0x80000000u) ? ~fu : (fu | 0x80000000u);
        unsigned long long key = ((unsigned long long)(~s) << 32) | (unsigned int)t;

        for (int k = 2; k <= NP; k <<= 1) {
            for (int j = k >> 1; j > 0; j >>= 1) {
                unsigned long long other;
                if (j < 64) {
                    other = __shfl_xor(key, j, 64);
                } else {
                    sk[t] = key;
                    __syncthreads();
                    other = sk[t ^ j];
                    __syncthreads();
                }
                bool take_min = (((t & k) == 0) == ((t & j) == 0));
                bool omin = other < key;
                key = (take_min == omin) ? other : key;
            }
        }
        // sort's internal barriers ordered scl[] writes before the reads below

        if (t < KK) {
            int idx  = (int)(key & 0xFFFFFFFFull);
            int node = g * NP + idx;
            int jj   = g * KK + t;
            perm_i[jj]   = node;
            new_id[node] = jj;
            out[OUT_PERM + jj]  = (float)node;
            out[OUT_BATCH + jj] = (float)g;   // graphs contiguous: batch == g
            factor[jj] = tanhf(scl[idx]);
        }
    }
    grid.sync();

    // ---------------- P4: gather + edge remap ------------------------------
    {
        // gather: x_new[j,:] = x[perm[j],:] * factor[j]
        const int base = blk * GROWS_PER_BLK;
        for (int r = w; r < GROWS_PER_BLK; r += 16) {
            const int j    = base + r;
            const int node = perm_i[j];
            const float f  = factor[j];
            float4 v = ((const float4*)(x + (size_t)node * D))[lane];
            ((float4*)(out + OUT_X + (size_t)j * D))[lane] =
                make_float4(v.x * f, v.y * f, v.z * f, v.w * f);
        }

        // edge remap with the graph's 4 KB new_id slice staged in LDS
        int* nid = (int*)sk;                // safe: last sk use was pre-grid.sync
        for (int i = t; i < NP; i += 1024) nid[i] = new_id[g2 * NP + i];
        __syncthreads();
        const size_t eo = (size_t)g2 * EPG + (size_t)half * EHALF;
        const int4* r4 = (const int4*)(rows + eo);
        const int4* c4 = (const int4*)(cols + eo);
        float4* orr = (float4*)(out + OUT_EI0  + eo);
        float4* occ = (float4*)(out + OUT_EI1  + eo);
        float4* omm = (float4*)(out + OUT_MASK + eo);
#pragma unroll
        for (int i = t; i < EHALF / 4; i += 1024) {     // 4 iters
            int4 r = r4[i];
            int4 c = c4[i];
            float4 fr, fc, fm;
            {
                int nr = nid[r.x & (NP - 1)], nc = nid[c.x & (NP - 1)];
                bool m = (nr >= 0) && (nc >= 0);
                fr.x = m ? (float)nr : -1.0f; fc.x = m ? (float)nc : -1.0f; fm.x = m ? 1.0f : 0.0f;
            }
            {
                int nr = nid[r.y & (NP - 1)], nc = nid[c.y & (NP - 1)];
                bool m = (nr >= 0) && (nc >= 0);
                fr.y = m ? (float)nr : -1.0f; fc.y = m ? (float)nc : -1.0f; fm.y = m ? 1.0f : 0.0f;
            }
            {
                int nr = nid[r.z & (NP - 1)], nc = nid[c.z & (NP - 1)];
                bool m = (nr >= 0) && (nc >= 0);
                fr.z = m ? (float)nr : -1.0f; fc.z = m ? (float)nc : -1.0f; fm.z = m ? 1.0f : 0.0f;
            }
            {
                int nr = nid[r.w & (NP - 1)], nc = nid[c.w & (NP - 1)];
                bool m = (nr >= 0) && (nc >= 0);
                fr.w = m ? (float)nr : -1.0f; fc.w = m ? (float)nc : -1.0f; fm.w = m ? 1.0f : 0.0f;
            }
            orr[i] = fr;
            occ[i] = fc;
            omm[i] = fm;
        }
    }
}

extern "C" void kernel_launch(void* const* d_in, const int* in_sizes, int n_in,
                              void* d_out, int out_size, void* d_ws, size_t ws_size,
                              hipStream_t stream) {
    (void)in_sizes; (void)n_in; (void)out_size; (void)ws_size;

    const float* x  = (const float*)d_in[0];
    const int*   ei = (const int*)d_in[1];
    // d_in[2] (batch) unused: graphs are contiguous so batch[node] = node/NP
    const float* W  = (const float*)d_in[3];
    const float* b  = (const float*)d_in[4];
    float* out = (float*)d_out;

    // Workspace layout (~4.0 MB; ws is poisoned each call -> all re-inited)
    float* wsf      = (float*)d_ws;
    float* h        = wsf;                                    // [NTOT]
    int*   new_id   = (int*)(wsf + NTOT);                     // [NTOT]
    int*   perm_i   = (int*)(wsf + 2 * NTOT);                 // [NKEEP]
    float* factor   = wsf + 2 * NTOT + NKEEP;                 // [NKEEP]
    int*   deg_part = (int*)(wsf + 2 * NTOT + 2 * NKEEP);     // [NBLK*NP]
    float* acc_part = wsf + 2 * NTOT + 2 * NKEEP + NBLK * NP; // [NBLK*NP]

    const int* rows = ei;        // edge_index[0] = sources
    const int* cols = ei + ET;   // edge_index[1] = targets

    void* args[] = { (void*)&x, (void*)&rows, (void*)&cols, (void*)&W, (void*)&b,
                     (void*)&h, (void*)&new_id, (void*)&perm_i, (void*)&factor,
                     (void*)&deg_part, (void*)&acc_part, (void*)&out };
    hipLaunchCooperativeKernel((const void*)fused_kernel, dim3(NBLK), dim3(1024),
                               args, 0, stream);
}

// Round 2
// 346.416 us; speedup vs baseline: 1.2871x; 1.2871x over previous
//
#include <hip/hip_runtime.h>
#include <math.h>

// Problem constants (fixed by the reference)
constexpr int NG    = 128;          // graphs
constexpr int NP    = 1024;         // nodes per graph
constexpr int D     = 256;          // feature dim
constexpr int NTOT  = NG * NP;      // 131072 nodes
constexpr int EPG   = NP * 32;      // 32768 edges per graph (contiguous slice)
constexpr int ET    = NTOT * 32;    // 4194304 edges
constexpr int KK    = 820;          // kept per graph
constexpr int NKEEP = NG * KK;      // 104960 kept nodes
constexpr int BPG   = 4;            // edge slices per graph
constexpr int EPB   = EPG / BPG;    // 8192 edges per slice
constexpr int NBE   = NG * BPG;     // 512 edge slices total

// Grid geometry
constexpr int K1_BLOCKS = 2048;     // 8 blocks/CU; waves = 8192; 16 rows/wave
constexpr int K4_BLOCKS = 2048;     // waves = 8192; ~13 gather rows/wave
constexpr int K1_ROWS_PER_WAVE = NTOT / (K1_BLOCKS * 4);   // 16

// Output layout (flat float32, reference return order)
constexpr long long OUT_X     = 0;
constexpr long long OUT_EI0   = (long long)NKEEP * D;     // 26869760
constexpr long long OUT_EI1   = OUT_EI0 + ET;
constexpr long long OUT_MASK  = OUT_EI0 + 2LL * ET;
constexpr long long OUT_BATCH = OUT_MASK + ET;
constexpr long long OUT_PERM  = OUT_BATCH + NKEEP;        // total 39662592

// ---------------------------------------------------------------------------
// K1: h[i] = dot(x[i,:], W) (wave-per-row, float4) + new_id=-1, grid-stride
//     2048 blocks. Blocks 0..511 additionally build one degree partial
//     (privatized LDS counters) over an 8192-edge slice.
__global__ __launch_bounds__(256) void k1_h_deg(const float* __restrict__ x,
                                                const float* __restrict__ W,
                                                const int* __restrict__ cols,
                                                float* __restrict__ h,
                                                int* __restrict__ new_id,
                                                int* __restrict__ deg_part) {
    __shared__ int cnt[NP];
    const int b    = blockIdx.x;
    const int t    = threadIdx.x;
    const int w    = t >> 6;
    const int lane = t & 63;
    const bool do_deg = (b < NBE);

    if (do_deg) {
        for (int i = t; i < NP; i += 256) cnt[i] = 0;
        __syncthreads();
    }

    // h pass: wave-per-row, 16 consecutive rows per wave
    float4 w4 = ((const float4*)W)[lane];
    const int base = (b * 4 + w) * K1_ROWS_PER_WAVE;
    for (int r = 0; r < K1_ROWS_PER_WAVE; ++r) {
        const int row = base + r;
        float4 a = ((const float4*)(x + (size_t)row * D))[lane];
        float s = a.x * w4.x + a.y * w4.y + a.z * w4.z + a.w * w4.w;
#pragma unroll
        for (int off = 32; off > 0; off >>= 1) s += __shfl_down(s, off, 64);
        if (lane == 0) { h[row] = s; new_id[row] = -1; }
    }

    if (do_deg) {
        const int g = b >> 2;
        const int4* c4 = (const int4*)(cols + (size_t)g * EPG + (size_t)(b & 3) * EPB);
#pragma unroll
        for (int i = t; i < EPB / 4; i += 256) {    // 8 iters
            int4 c = c4[i];
            atomicAdd(&cnt[c.x & (NP - 1)], 1);
            atomicAdd(&cnt[c.y & (NP - 1)], 1);
            atomicAdd(&cnt[c.z & (NP - 1)], 1);
            atomicAdd(&cnt[c.w & (NP - 1)], 1);
        }
        __syncthreads();
        int* dst = deg_part + (size_t)b * NP;
        for (int i = t; i < NP; i += 256) dst[i] = cnt[i];
    }
}

// ---------------------------------------------------------------------------
// K2: aggregation partials. Each block rebuilds u = rsqrt(deg)*h for its graph
//     from the 4 degree partials (L2-resident), then acc[c] += u[r] over its
//     8192-edge slice in private LDS.
__global__ __launch_bounds__(256) void k2_acc(const int* __restrict__ rows,
                                              const int* __restrict__ cols,
                                              const float* __restrict__ h,
                                              const int* __restrict__ deg_part,
                                              float* __restrict__ acc_part) {
    __shared__ float ul[NP];
    __shared__ float acc[NP];
    const int b = blockIdx.x;
    const int g = b >> 2;
    const int* dp = deg_part + (size_t)g * BPG * NP;
    for (int i = threadIdx.x; i < NP; i += 256) {
        int d = 1 + dp[i] + dp[NP + i] + dp[2 * NP + i] + dp[3 * NP + i];
        ul[i]  = rsqrtf((float)d) * h[g * NP + i];
        acc[i] = 0.0f;
    }
    __syncthreads();
    size_t eoff = (size_t)g * EPG + (size_t)(b & 3) * EPB;
    const int4* c4 = (const int4*)(cols + eoff);
    const int4* r4 = (const int4*)(rows + eoff);
#pragma unroll
    for (int i = threadIdx.x; i < EPB / 4; i += 256) {   // 8 iters
        int4 c = c4[i];
        int4 r = r4[i];
        atomicAdd(&acc[c.x & (NP - 1)], ul[r.x & (NP - 1)]);
        atomicAdd(&acc[c.y & (NP - 1)], ul[r.y & (NP - 1)]);
        atomicAdd(&acc[c.z & (NP - 1)], ul[r.z & (NP - 1)]);
        atomicAdd(&acc[c.w & (NP - 1)], ul[r.w & (NP - 1)]);
    }
    __syncthreads();
    float* dst = acc_part + (size_t)b * NP;
    for (int i = threadIdx.x; i < NP; i += 256) dst[i] = acc[i];
}

// ---------------------------------------------------------------------------
// K3: combine partials -> score -> register bitonic top-k -> epilogue.
//     One 1024-thread block per graph. 45/55 bitonic steps via __shfl_xor,
//     10 cross-wave steps via LDS.
__global__ __launch_bounds__(1024) void k3_sort(
        const float* __restrict__ h, const float* __restrict__ b,
        const int* __restrict__ deg_part, const float* __restrict__ acc_part,
        int* __restrict__ perm_i, int* __restrict__ new_id,
        float* __restrict__ factor,
        float* __restrict__ out_perm, float* __restrict__ out_batch) {
    __shared__ unsigned long long sk[NP];    // sort exchange buffer (8 KB)
    __shared__ float scl[NP];                // final scores for epilogue tanh

    const int g = blockIdx.x;
    const int t = threadIdx.x;
    const int*   dp = deg_part + (size_t)g * BPG * NP;
    const float* ap = acc_part + (size_t)g * BPG * NP;

    int   d  = 1 + dp[t] + dp[NP + t] + dp[2 * NP + t] + dp[3 * NP + t];
    float av = ap[t] + ap[NP + t] + ap[2 * NP + t] + ap[3 * NP + t];
    float hv = h[g * NP + t];
    float di = rsqrtf((float)d);
    float score = di * av + di * di * hv + b[0];
    scl[t] = score;

    // pack sortable key: ascending u64 == (descending score, ascending idx)
    unsigned int fu = __float_as_uint(score);
    unsigned int s  = (fu & 0x80000000u) ? ~fu : (fu | 0x80000000u);
    unsigned long long key = ((unsigned long long)(~s) << 32) | (unsigned int)t;

    for (int k = 2; k <= NP; k <<= 1) {
        for (int j = k >> 1; j > 0; j >>= 1) {
            unsigned long long other;
            if (j < 64) {
                other = __shfl_xor(key, j, 64);
            } else {
                sk[t] = key;
                __syncthreads();
                other = sk[t ^ j];
                __syncthreads();
            }
            bool take_min = (((t & k) == 0) == ((t & j) == 0));
            bool omin = other < key;
            key = (take_min == omin) ? other : key;
        }
    }
    // sort's internal barriers ordered scl[] writes before the reads below

    if (t < KK) {
        int idx  = (int)(key & 0xFFFFFFFFull);
        int node = g * NP + idx;
        int j    = g * KK + t;
        perm_i[j]    = node;
        new_id[node] = j;
        out_perm[j]  = (float)node;
        out_batch[j] = (float)g;         // graphs contiguous: batch[node] == g
        factor[j]    = tanhf(scl[idx]);  // gather scale, precomputed
    }
}

// ---------------------------------------------------------------------------
// K4: fused gather + edge remap. 2048 blocks x 256.
//     Blocks 0..511: remap one 8192-edge slice via the graph's 4 KB new_id
//     slice staged in LDS. All blocks: grid-stride wave-per-row gather.
__global__ __launch_bounds__(256) void k4_gather_edge(
        const float* __restrict__ x,
        const int* __restrict__ rows, const int* __restrict__ cols,
        const int* __restrict__ new_id,
        const int* __restrict__ perm_i, const float* __restrict__ factor,
        float* __restrict__ out) {
    __shared__ int nid[NP];
    const int b    = blockIdx.x;
    const int t    = threadIdx.x;
    const int w    = t >> 6;
    const int lane = t & 63;

    if (b < NBE) {
        const int g = b >> 2;
        for (int i = t; i < NP; i += 256) nid[i] = new_id[g * NP + i];
        __syncthreads();
        size_t eoff = (size_t)g * EPG + (size_t)(b & 3) * EPB;
        const int4* r4 = (const int4*)(rows + eoff);
        const int4* c4 = (const int4*)(cols + eoff);
        float4* orr = (float4*)(out + OUT_EI0  + eoff);
        float4* occ = (float4*)(out + OUT_EI1  + eoff);
        float4* omm = (float4*)(out + OUT_MASK + eoff);
#pragma unroll
        for (int i = t; i < EPB / 4; i += 256) {   // 8 iters
            int4 r = r4[i];
            int4 c = c4[i];
            float4 fr, fc, fm;
            {
                int nr = nid[r.x & (NP - 1)], nc = nid[c.x & (NP - 1)];
                bool m = (nr >= 0) && (nc >= 0);
                fr.x = m ? (float)nr : -1.0f; fc.x = m ? (float)nc : -1.0f; fm.x = m ? 1.0f : 0.0f;
            }
            {
                int nr = nid[r.y & (NP - 1)], nc = nid[c.y & (NP - 1)];
                bool m = (nr >= 0) && (nc >= 0);
                fr.y = m ? (float)nr : -1.0f; fc.y = m ? (float)nc : -1.0f; fm.y = m ? 1.0f : 0.0f;
            }
            {
                int nr = nid[r.z & (NP - 1)], nc = nid[c.z & (NP - 1)];
                bool m = (nr >= 0) && (nc >= 0);
                fr.z = m ? (float)nr : -1.0f; fc.z = m ? (float)nc : -1.0f; fm.z = m ? 1.0f : 0.0f;
            }
            {
                int nr = nid[r.w & (NP - 1)], nc = nid[c.w & (NP - 1)];
                bool m = (nr >= 0) && (nc >= 0);
                fr.w = m ? (float)nr : -1.0f; fc.w = m ? (float)nc : -1.0f; fm.w = m ? 1.0f : 0.0f;
            }
            orr[i] = fr;
            occ[i] = fc;
            omm[i] = fm;
        }
    }

    // gather: x_new[j,:] = x[perm[j],:] * factor[j]; wave-per-row grid-stride
    const int gw = b * 4 + w;                      // 0..8191
    for (int j = gw; j < NKEEP; j += K4_BLOCKS * 4) {
        const int node = perm_i[j];
        const float f  = factor[j];
        float4 v = ((const float4*)(x + (size_t)node * D))[lane];
        ((float4*)(out + OUT_X + (size_t)j * D))[lane] =
            make_float4(v.x * f, v.y * f, v.z * f, v.w * f);
    }
}

extern "C" void kernel_launch(void* const* d_in, const int* in_sizes, int n_in,
                              void* d_out, int out_size, void* d_ws, size_t ws_size,
                              hipStream_t stream) {
    (void)in_sizes; (void)n_in; (void)out_size; (void)ws_size;

    const float* x  = (const float*)d_in[0];
    const int*   ei = (const int*)d_in[1];
    // d_in[2] (batch) unused: graphs are contiguous so batch[node] = node/NP
    const float* W  = (const float*)d_in[3];
    const float* b  = (const float*)d_in[4];
    float* out = (float*)d_out;

    // Workspace layout (~6.4 MB; ws is poisoned each call -> all re-inited)
    float* wsf      = (float*)d_ws;
    float* h        = wsf;                                    // [NTOT]
    int*   new_id   = (int*)(wsf + NTOT);                     // [NTOT]
    int*   perm_i   = (int*)(wsf + 2 * NTOT);                 // [NKEEP]
    float* factor   = wsf + 2 * NTOT + NKEEP;                 // [NKEEP]
    int*   deg_part = (int*)(wsf + 2 * NTOT + 2 * NKEEP);     // [NBE*NP]
    float* acc_part = wsf + 2 * NTOT + 2 * NKEEP + NBE * NP;  // [NBE*NP]

    const int* rows = ei;        // edge_index[0] = sources
    const int* cols = ei + ET;   // edge_index[1] = targets

    hipLaunchKernelGGL(k1_h_deg, dim3(K1_BLOCKS), dim3(256), 0, stream,
                       x, W, cols, h, new_id, deg_part);
    hipLaunchKernelGGL(k2_acc, dim3(NBE), dim3(256), 0, stream,
                       rows, cols, h, deg_part, acc_part);
    hipLaunchKernelGGL(k3_sort, dim3(NG), dim3(1024), 0, stream,
                       h, b, deg_part, acc_part, perm_i, new_id, factor,
                       out + OUT_PERM, out + OUT_BATCH);
    hipLaunchKernelGGL(k4_gather_edge, dim3(K4_BLOCKS), dim3(256), 0, stream,
                       x, rows, cols, new_id, perm_i, factor, out + OUT_X);
}